// Round 9
// baseline (936.490 us; speedup 1.0000x reference)
//
#include <hip/hip_runtime.h>
#include <math.h>

// Problem constants (match reference)
#define MB 8      // batch
#define MM 384    // checks
#define NN 1536   // variables
#define LL 20     // layers
#define RW 8      // row weight of H
#define HE 4      // edges per thread (half row)
#define NE (MM*RW)  // 3072 edges
#define NT 768    // bp block size (2 threads per check row)

#define REP_SCALE 4ULL       // amplify phases past the top-5 visibility filter
#define REP_CAP 2400000ULL   // 1 ms max per reporter (guards 0xAA poison too)

// ---------------------------------------------------------------------------
// Phase reporters: spin for diag[i]*4 core ticks.
// True phase time (us) = displayed dur_us / 4.
// ---------------------------------------------------------------------------
__global__ void rep_p0(const unsigned long long* diag, unsigned long long* sink) {
    if (threadIdx.x == 0) {
        unsigned long long tgt = diag[0] * REP_SCALE; if (tgt > REP_CAP) tgt = REP_CAP;
        unsigned long long t0 = clock64(), it = 0;
        while (clock64() - t0 < tgt) ++it;
        sink[1] = it;
    }
}
__global__ void rep_p1(const unsigned long long* diag, unsigned long long* sink) {
    if (threadIdx.x == 0) {
        unsigned long long tgt = diag[1] * REP_SCALE; if (tgt > REP_CAP) tgt = REP_CAP;
        unsigned long long t0 = clock64(), it = 0;
        while (clock64() - t0 < tgt) ++it;
        sink[2] = it;
    }
}
__global__ void rep_p2(const unsigned long long* diag, unsigned long long* sink) {
    if (threadIdx.x == 0) {
        unsigned long long tgt = diag[2] * REP_SCALE; if (tgt > REP_CAP) tgt = REP_CAP;
        unsigned long long t0 = clock64(), it = 0;
        while (clock64() - t0 < tgt) ++it;
        sink[3] = it;
    }
}
__global__ void rep_p3(const unsigned long long* diag, unsigned long long* sink) {
    if (threadIdx.x == 0) {
        unsigned long long tgt = diag[3] * REP_SCALE; if (tgt > REP_CAP) tgt = REP_CAP;
        unsigned long long t0 = clock64(), it = 0;
        while (clock64() - t0 < tgt) ++it;
        sink[4] = it;
    }
}

// ---------------------------------------------------------------------------
// Fused setup: one block (256 thr = 4 waves) per check row (unchanged).
// ---------------------------------------------------------------------------
__global__ __launch_bounds__(256) void setup_kernel(
    const float* __restrict__ H,
    const float* __restrict__ llrs,
    const float* __restrict__ w_llr,
    const float* __restrict__ w_de,
    const float* __restrict__ marg_de,
    int*   __restrict__ col_idx,
    float* __restrict__ marg_e,
    float* __restrict__ base_e,
    float* __restrict__ wde_e,
    float* __restrict__ out) {
    const int m = blockIdx.x;
    const int t = threadIdx.x;
    const int w = t >> 6, lane = t & 63;
    __shared__ int s_qcol[4][RW];
    __shared__ int s_qcnt[4];
    __shared__ int s_col[RW];

    const float* row = H + (size_t)m * NN;
    int count = 0;
    for (int c0 = w * 384; c0 < (w + 1) * 384; c0 += 64) {
        float v = row[c0 + lane];
        unsigned long long mask = __ballot(v != 0.0f);
        if (v != 0.0f) {
            int pos = count + (int)__popcll(mask & ((1ull << lane) - 1ull));
            if (pos < RW) s_qcol[w][pos] = c0 + lane;
        }
        count += (int)__popcll(mask);
    }
    if (lane == 0) s_qcnt[w] = (count < RW) ? count : RW;
    __syncthreads();
    if (t == 0) {
        int off = 0;
        for (int q = 0; q < 4; ++q)
            for (int i = 0; i < s_qcnt[q]; ++i) {
                if (off < RW) s_col[off] = s_qcol[q][i];
                ++off;
            }
    }
    __syncthreads();

    if (t < RW) {
        int c = s_col[t];
        col_idx[m * RW + t] = c;
        marg_e[m * RW + t]  = marg_de[m * NN + c];
    }
    if (m == 0 && t == 0) out[0] = 0.0f;

    for (int idx = t; idx < LL * RW; idx += 256) {
        int l = idx >> 3;
        int k = idx & 7;
        int c = s_col[k];
        base_e[l * NE + m * RW + k] = llrs[c] * w_llr[l * NN + c];
        wde_e [l * NE + m * RW + k] = w_de[(size_t)l * MM * NN + (size_t)m * NN + c];
    }
}

// ---------------------------------------------------------------------------
// Main BP kernel — byte-identical structure to R8 (phase timers included).
//  P0: prefetch issue + deferred loss + resets
//  P1: S-gather + check compute + shfl + per-k math + scatter ISSUE
//  P2: s_waitcnt vmcnt(0) lgkmcnt(0)  (atomic + weight-load completion)
//  P3: __syncthreads residual (inter-wave skew)
// ---------------------------------------------------------------------------
__global__ __launch_bounds__(NT) void bp_kernel(
    const float* __restrict__ synd,
    const float* __restrict__ errors,
    const float* __restrict__ llrs,
    const float* __restrict__ marg_llr,
    const float* __restrict__ res_w,
    const float* __restrict__ rhos,
    const int*   __restrict__ col_idx,
    const float* __restrict__ marg_e_g,
    const float* __restrict__ base_e_g,
    const float* __restrict__ wde_e_g,
    float* __restrict__ out,
    unsigned long long* __restrict__ diag) {

    __shared__ float s_S[3][NN];
    __shared__ float s_bel[2][NN];
    __shared__ float s_rw[LL];
    __shared__ float s_rho[LL];
    __shared__ float s_red[12];

    const int b = blockIdx.x;
    const int t = threadIdx.x;
    const int m = t >> 1;

    int col[HE];
    {
        const int4 ci = ((const int4*)col_idx)[t];
        col[0] = ci.x; col[1] = ci.y; col[2] = ci.z; col[3] = ci.w;
    }
    float msg[HE] = {0.0f, 0.0f, 0.0f, 0.0f};
    float marg[HE];
    {
        const float4 mg = ((const float4*)marg_e_g)[t];
        marg[0] = mg.x; marg[1] = mg.y; marg[2] = mg.z; marg[3] = mg.w;
    }
    const float sgn = 1.0f - 2.0f * synd[b * MM + m];

    float bias[2], omeg[2];
    #pragma unroll
    for (int i = 0; i < 2; ++i) {
        int n = t + i * NT;
        bias[i] = llrs[n] * marg_llr[n];
        omeg[i] = 1.0f - errors[b * NN + n];
        s_S[0][n] = 0.0f; s_S[1][n] = 0.0f; s_S[2][n] = 0.0f;
        s_bel[0][n] = bias[i]; s_bel[1][n] = bias[i];
    }
    if (t < LL) { s_rw[t] = res_w[t]; s_rho[t] = rhos[t]; }

    float bc[HE], wS[HE], bn[HE], wn2[HE];
    {
        const float4 bp4 = ((const float4*)(base_e_g))[t];
        bc[0] = bp4.x; bc[1] = bp4.y; bc[2] = bp4.z; bc[3] = bp4.w;
        const float4 wp4 = ((const float4*)(wde_e_g + 1 * NE))[t];
        wS[0] = wp4.x; wS[1] = wp4.y; wS[2] = wp4.z; wS[3] = wp4.w;
    }

    float loss = 0.0f;
    unsigned long long p0 = 0, p1 = 0, p2 = 0, p3 = 0;
    __syncthreads();

    for (int l = 0; l < LL; ++l) {
        unsigned long long tA = clock64();

        {
            int lb = (l + 1 < LL) ? (l + 1) : (LL - 1);
            int lw = (l + 2 < LL) ? (l + 2) : (LL - 1);
            const float4 bp4 = ((const float4*)(base_e_g + lb * NE))[t];
            bn[0]  = bp4.x; bn[1]  = bp4.y; bn[2]  = bp4.z; bn[3]  = bp4.w;
            const float4 wp4 = ((const float4*)(wde_e_g + lw * NE))[t];
            wn2[0] = wp4.x; wn2[1] = wp4.y; wn2[2] = wp4.z; wn2[3] = wp4.w;
        }

        if (l > 0) {
            const float rr = s_rho[l - 1];
            const int   pb = (l - 1) & 1;
            float acc = 0.0f;
            #pragma unroll
            for (int i = 0; i < 2; ++i) {
                int n = t + i * NT;
                float be = s_bel[pb][n];
                float sp = fmaxf(be, 0.0f) + __logf(1.0f + __expf(-fabsf(be)));
                acc += sp - omeg[i] * be;
                s_bel[pb][n] = bias[i];
            }
            loss += rr * acc;
        }

        {
            const int sb = (l + 2) % 3;
            s_S[sb][t] = 0.0f;
            s_S[sb][t + NT] = 0.0f;
        }

        unsigned long long tB = clock64();

        const float rw_ = s_rw[l];
        const int cs = l % 3, ns = (l + 1) % 3, bb = l & 1;

        float d[HE];
        #pragma unroll
        for (int k = 0; k < HE; ++k) {
            float te = bc[k] + s_S[cs][col[k]] - msg[k];
            float e  = __expf(te);
            float dd = 1.0f - 2.0f * __builtin_amdgcn_rcpf(e + 1.0f);
            dd = fminf(fmaxf(dd, -1.0f), 1.0f);
            if (dd == 0.0f) dd = 1.0f;
            d[k] = dd;
        }
        float p01 = d[0] * d[1], p23 = d[2] * d[3];
        float p4  = p01 * p23;
        float pot = __shfl_xor(p4, 1, 64);
        float ptot = p4 * pot;

        #pragma unroll
        for (int k = 0; k < HE; ++k) {
            float x  = ptot * __builtin_amdgcn_rcpf(d[k]);
            float r  = (1.0f + x) * __builtin_amdgcn_rcpf(1.0f - x);
            float nm = sgn * __logf(r) + rw_ * msg[k];
            msg[k] = nm;
            unsafeAtomicAdd(&s_S[ns][col[k]], nm * wS[k]);
            unsafeAtomicAdd(&s_bel[bb][col[k]], nm * marg[k]);
        }

        #pragma unroll
        for (int k = 0; k < HE; ++k) { bc[k] = bn[k]; wS[k] = wn2[k]; }

        unsigned long long tC = clock64();
        asm volatile("s_waitcnt vmcnt(0) lgkmcnt(0)" ::: "memory");
        unsigned long long tD = clock64();
        __syncthreads();
        unsigned long long tE = clock64();

        p0 += tB - tA; p1 += tC - tB; p2 += tD - tC; p3 += tE - tD;
    }

    {
        const float rr = s_rho[LL - 1];
        const int   pb = (LL - 1) & 1;
        float acc = 0.0f;
        #pragma unroll
        for (int i = 0; i < 2; ++i) {
            int n = t + i * NT;
            float be = s_bel[pb][n];
            float sp = fmaxf(be, 0.0f) + __logf(1.0f + __expf(-fabsf(be)));
            acc += sp - omeg[i] * be;
        }
        loss += rr * acc;
    }

    #pragma unroll
    for (int off = 32; off > 0; off >>= 1)
        loss += __shfl_down(loss, off, 64);
    int wave = t >> 6, lane = t & 63;
    if (lane == 0) s_red[wave] = loss;
    __syncthreads();
    if (t == 0) {
        float tot = 0.0f;
        #pragma unroll
        for (int w = 0; w < 12; ++w) tot += s_red[w];
        atomicAdd(out, tot * (1.0f / (float)MB));
        if (b == 0) { diag[0] = p0; diag[1] = p1; diag[2] = p2; diag[3] = p3; }
    }
}

// ---------------------------------------------------------------------------
extern "C" void kernel_launch(void* const* d_in, const int* in_sizes, int n_in,
                              void* d_out, int out_size, void* d_ws, size_t ws_size,
                              hipStream_t stream) {
    const float* synd     = (const float*)d_in[0];
    const float* errors   = (const float*)d_in[1];
    const float* H        = (const float*)d_in[2];
    const float* llrs     = (const float*)d_in[3];
    const float* w_de     = (const float*)d_in[4];
    const float* w_llr    = (const float*)d_in[5];
    const float* marg_de  = (const float*)d_in[6];
    const float* marg_llr = (const float*)d_in[7];
    const float* res_w    = (const float*)d_in[8];
    const float* rhos     = (const float*)d_in[9];
    float* out = (float*)d_out;

    int*   col_idx = (int*)d_ws;            // NE ints
    float* marg_e  = (float*)d_ws + NE;     // NE floats
    float* base_e  = marg_e + NE;           // L*NE floats
    float* wde_e   = base_e + LL * NE;      // L*NE floats
    unsigned long long* diag =
        (unsigned long long*)((char*)d_ws + ws_size - 128);   // 4 ULL timers
    unsigned long long* sink =
        (unsigned long long*)((char*)d_ws + ws_size - 64);    // reporter sinks

    setup_kernel<<<MM, 256, 0, stream>>>(H, llrs, w_llr, w_de, marg_de,
                                         col_idx, marg_e, base_e, wde_e, out);
    bp_kernel<<<MB, NT, 0, stream>>>(synd, errors, llrs, marg_llr, res_w, rhos,
                                     col_idx, marg_e, base_e, wde_e, out, diag);
    // Diagnostics: TRUE phase-i time (us) = displayed dur_us / 4
    rep_p0<<<1, 64, 0, stream>>>(diag, sink);
    rep_p1<<<1, 64, 0, stream>>>(diag, sink);
    rep_p2<<<1, 64, 0, stream>>>(diag, sink);
    rep_p3<<<1, 64, 0, stream>>>(diag, sink);
}

// Round 10
// 209.075 us; speedup vs baseline: 4.4792x; 4.4792x over previous
//
#include <hip/hip_runtime.h>
#include <math.h>

// Problem constants (match reference)
#define MB 8      // batch
#define MM 384    // checks
#define NN 1536   // variables
#define LL 20     // layers
#define RW 8      // row weight of H
#define HE 4      // edges per thread (half row)
#define NE (MM*RW)  // 3072 edges
#define NT 768    // bp block size (2 threads per check row)
#define VP 12     // max column degree supported (Poisson(2) tail: P(deg>12)~1e-7)

// ---------------------------------------------------------------------------
// Fused setup: one block (256 thr = 4 waves) per check row.
//  4-wave ballot scan of H row m -> RW column indices (order-preserving),
//  then gather all per-layer edge weights into contiguous ws arrays.
//  Block 0 zeroes the output scalar.
// ---------------------------------------------------------------------------
__global__ __launch_bounds__(256) void setup_kernel(
    const float* __restrict__ H,
    const float* __restrict__ llrs,
    const float* __restrict__ w_llr,
    const float* __restrict__ w_de,
    const float* __restrict__ marg_de,
    int*   __restrict__ col_idx,
    float* __restrict__ marg_e,
    float* __restrict__ base_e,
    float* __restrict__ wde_e,
    float* __restrict__ out) {
    const int m = blockIdx.x;
    const int t = threadIdx.x;
    const int w = t >> 6, lane = t & 63;
    __shared__ int s_qcol[4][RW];
    __shared__ int s_qcnt[4];
    __shared__ int s_col[RW];

    const float* row = H + (size_t)m * NN;
    int count = 0;
    for (int c0 = w * 384; c0 < (w + 1) * 384; c0 += 64) {
        float v = row[c0 + lane];
        unsigned long long mask = __ballot(v != 0.0f);
        if (v != 0.0f) {
            int pos = count + (int)__popcll(mask & ((1ull << lane) - 1ull));
            if (pos < RW) s_qcol[w][pos] = c0 + lane;
        }
        count += (int)__popcll(mask);
    }
    if (lane == 0) s_qcnt[w] = (count < RW) ? count : RW;
    __syncthreads();
    if (t == 0) {
        int off = 0;
        for (int q = 0; q < 4; ++q)
            for (int i = 0; i < s_qcnt[q]; ++i) {
                if (off < RW) s_col[off] = s_qcol[q][i];
                ++off;
            }
    }
    __syncthreads();

    if (t < RW) {
        int c = s_col[t];
        col_idx[m * RW + t] = c;
        marg_e[m * RW + t]  = marg_de[m * NN + c];
    }
    if (m == 0 && t == 0) out[0] = 0.0f;

    for (int idx = t; idx < LL * RW; idx += 256) {
        int l = idx >> 3;
        int k = idx & 7;
        int c = s_col[k];
        base_e[l * NE + m * RW + k] = llrs[c] * w_llr[l * NN + c];
        wde_e [l * NE + m * RW + k] = w_de[(size_t)l * MM * NN + (size_t)m * NN + c];
    }
}

// ---------------------------------------------------------------------------
// Main BP kernel: 8 blocks, 768 threads = 2 per check row (4 edges each).
// ONE barrier per layer.
//   - S (variable sums): LDS 3-buffer rotation, scatter via native ds_add_f32
//     (the remaining atomics — 4/thread/layer).
//   - beliefs: NO atomics. Each edge WRITES its contribution nm*marg to a
//     private slot in a dense double-buffered LDS array cB; the deferred-loss
//     phase (one layer later) GATHERS each variable's incident slots via a
//     CSC slot table built once in LDS at kernel start (avg col degree = 2).
//   - per-edge weights: coalesced float4 loads, prefetched one layer ahead.
// ---------------------------------------------------------------------------
__global__ __launch_bounds__(NT) void bp_kernel(
    const float* __restrict__ synd,       // (B,M,1)
    const float* __restrict__ errors,     // (B,N)
    const float* __restrict__ llrs,       // (N)
    const float* __restrict__ marg_llr,   // (N)
    const float* __restrict__ res_w,      // (L)
    const float* __restrict__ rhos,       // (L)
    const int*   __restrict__ col_idx,    // (E)
    const float* __restrict__ marg_e_g,   // (E)
    const float* __restrict__ base_e_g,   // (L,E)
    const float* __restrict__ wde_e_g,    // (L,E)
    float* __restrict__ out) {

    __shared__ float s_S[3][NN];              // 18 KB
    __shared__ float s_cB[2][NE];             // 24 KB  belief contribs, [buf][k*NT+t]
    __shared__ unsigned short s_vslot[NN*VP]; // 36 KB  CSC slot table
    __shared__ int   s_vdeg[NN];              // 6 KB
    __shared__ float s_rw[LL];
    __shared__ float s_rho[LL];
    __shared__ float s_red[12];

    const int b = blockIdx.x;
    const int t = threadIdx.x;
    const int m = t >> 1;        // check row; edges owned: e = t*HE + k

    // ---- per-thread register state ----
    int col[HE];
    {
        const int4 ci = ((const int4*)col_idx)[t];
        col[0] = ci.x; col[1] = ci.y; col[2] = ci.z; col[3] = ci.w;
    }
    float msg[HE] = {0.0f, 0.0f, 0.0f, 0.0f};
    float marg[HE];
    {
        const float4 mg = ((const float4*)marg_e_g)[t];
        marg[0] = mg.x; marg[1] = mg.y; marg[2] = mg.z; marg[3] = mg.w;
    }
    const float sgn = 1.0f - 2.0f * synd[b * MM + m];

    float bias[2], omeg[2];
    #pragma unroll
    for (int i = 0; i < 2; ++i) {
        int n = t + i * NT;
        bias[i] = llrs[n] * marg_llr[n];
        omeg[i] = 1.0f - errors[b * NN + n];
        s_S[0][n] = 0.0f; s_S[1][n] = 0.0f; s_S[2][n] = 0.0f;
        s_vdeg[n] = 0;
    }
    if (t < LL) { s_rw[t] = res_w[t]; s_rho[t] = rhos[t]; }
    __syncthreads();

    // ---- build CSC slot table (once): edge (t,k) -> slot k*NT+t under col[k]
    #pragma unroll
    for (int k = 0; k < HE; ++k) {
        int c = col[k];
        int pos = atomicAdd(&s_vdeg[c], 1);
        if (pos < VP) s_vslot[c * VP + pos] = (unsigned short)(k * NT + t);
    }
    __syncthreads();

    // ---- cache own variables' slot lists in registers ----
    int deg0 = s_vdeg[t];        if (deg0 > VP) deg0 = VP;
    int deg1 = s_vdeg[t + NT];   if (deg1 > VP) deg1 = VP;
    int sl0[VP], sl1[VP];
    #pragma unroll
    for (int j = 0; j < VP; ++j) {
        sl0[j] = (j < deg0) ? (int)s_vslot[t * VP + j] : 0;
        sl1[j] = (j < deg1) ? (int)s_vslot[(t + NT) * VP + j] : 0;
    }

    // ---- prefetch: bc = base_e[layer 0], wS = wde_e[layer 1] ----
    float bc[HE], wS[HE], bn[HE], wn2[HE];
    {
        const float4 bp4 = ((const float4*)(base_e_g))[t];
        bc[0] = bp4.x; bc[1] = bp4.y; bc[2] = bp4.z; bc[3] = bp4.w;
        const float4 wp4 = ((const float4*)(wde_e_g + 1 * NE))[t];
        wS[0] = wp4.x; wS[1] = wp4.y; wS[2] = wp4.z; wS[3] = wp4.w;
    }

    float loss = 0.0f;
    __syncthreads();

    for (int l = 0; l < LL; ++l) {
        // prefetch base_e[l+1] and wde_e[l+2] (consumed next layer)
        {
            int lb = (l + 1 < LL) ? (l + 1) : (LL - 1);
            int lw = (l + 2 < LL) ? (l + 2) : (LL - 1);
            const float4 bp4 = ((const float4*)(base_e_g + lb * NE))[t];
            bn[0]  = bp4.x; bn[1]  = bp4.y; bn[2]  = bp4.z; bn[3]  = bp4.w;
            const float4 wp4 = ((const float4*)(wde_e_g + lw * NE))[t];
            wn2[0] = wp4.x; wn2[1] = wp4.y; wn2[2] = wp4.z; wn2[3] = wp4.w;
        }

        // deferred loss for layer l-1: gather belief contribs (no atomics)
        if (l > 0) {
            const float rr = s_rho[l - 1];
            const float* cb = s_cB[(l - 1) & 1];
            float bel0 = bias[0], bel1 = bias[1];
            #pragma unroll
            for (int j = 0; j < VP; ++j) {
                if (j < deg0) bel0 += cb[sl0[j]];
                if (j < deg1) bel1 += cb[sl1[j]];
            }
            float sp0 = fmaxf(bel0, 0.0f) + __logf(1.0f + __expf(-fabsf(bel0)));
            float sp1 = fmaxf(bel1, 0.0f) + __logf(1.0f + __expf(-fabsf(bel1)));
            loss += rr * ((sp0 - omeg[0] * bel0) + (sp1 - omeg[1] * bel1));
        }

        // reset the idle S buffer (owned slots; consumed two layers ago)
        {
            const int sb = (l + 2) % 3;
            s_S[sb][t] = 0.0f;
            s_S[sb][t + NT] = 0.0f;
        }

        const float rw_ = s_rw[l];
        const int cs = l % 3, ns = (l + 1) % 3;
        float* cbw = s_cB[l & 1];

        // check-node update over this thread's 4 edges
        float d[HE];
        #pragma unroll
        for (int k = 0; k < HE; ++k) {
            float te = bc[k] + s_S[cs][col[k]] - msg[k];
            float e  = __expf(te);                          // v_exp_f32
            float dd = 1.0f - 2.0f * __builtin_amdgcn_rcpf(e + 1.0f);
            dd = fminf(fmaxf(dd, -1.0f), 1.0f);             // guard rcp rounding
            if (dd == 0.0f) dd = 1.0f;                      // jnp.where(d==0,1,d)
            d[k] = dd;
        }
        float p01 = d[0] * d[1], p23 = d[2] * d[3];
        float p4  = p01 * p23;
        float pot = __shfl_xor(p4, 1, 64);                  // partner half's product
        float ptot = p4 * pot;                              // full row product

        #pragma unroll
        for (int k = 0; k < HE; ++k) {
            float x  = ptot * __builtin_amdgcn_rcpf(d[k]);  // reference's p/d
            float r  = (1.0f + x) * __builtin_amdgcn_rcpf(1.0f - x);
            float nm = sgn * __logf(r) + rw_ * msg[k];      // 2*atanh*sgn + res*msg
            msg[k] = nm;
            unsafeAtomicAdd(&s_S[ns][col[k]], nm * wS[k]);  // S scatter (atomic)
            cbw[k * NT + t] = nm * marg[k];                 // bel contrib (plain write)
        }

        // rotate prefetched weights
        #pragma unroll
        for (int k = 0; k < HE; ++k) { bc[k] = bn[k]; wS[k] = wn2[k]; }

        __syncthreads();   // the ONE barrier per layer
    }

    // tail: loss for the last layer
    {
        const float rr = s_rho[LL - 1];
        const float* cb = s_cB[(LL - 1) & 1];
        float bel0 = bias[0], bel1 = bias[1];
        #pragma unroll
        for (int j = 0; j < VP; ++j) {
            if (j < deg0) bel0 += cb[sl0[j]];
            if (j < deg1) bel1 += cb[sl1[j]];
        }
        float sp0 = fmaxf(bel0, 0.0f) + __logf(1.0f + __expf(-fabsf(bel0)));
        float sp1 = fmaxf(bel1, 0.0f) + __logf(1.0f + __expf(-fabsf(bel1)));
        loss += rr * ((sp0 - omeg[0] * bel0) + (sp1 - omeg[1] * bel1));
    }

    // ---- block-wide loss reduction (12 waves) ----
    #pragma unroll
    for (int off = 32; off > 0; off >>= 1)
        loss += __shfl_down(loss, off, 64);
    int wave = t >> 6, lane = t & 63;
    if (lane == 0) s_red[wave] = loss;
    __syncthreads();
    if (t == 0) {
        float tot = 0.0f;
        #pragma unroll
        for (int w = 0; w < 12; ++w) tot += s_red[w];
        atomicAdd(out, tot * (1.0f / (float)MB));
    }
}

// ---------------------------------------------------------------------------
extern "C" void kernel_launch(void* const* d_in, const int* in_sizes, int n_in,
                              void* d_out, int out_size, void* d_ws, size_t ws_size,
                              hipStream_t stream) {
    const float* synd     = (const float*)d_in[0];
    const float* errors   = (const float*)d_in[1];
    const float* H        = (const float*)d_in[2];
    const float* llrs     = (const float*)d_in[3];
    const float* w_de     = (const float*)d_in[4];
    const float* w_llr    = (const float*)d_in[5];
    const float* marg_de  = (const float*)d_in[6];
    const float* marg_llr = (const float*)d_in[7];
    const float* res_w    = (const float*)d_in[8];
    const float* rhos     = (const float*)d_in[9];
    float* out = (float*)d_out;

    // Workspace layout (4-byte elements, 16B-aligned partitions)
    int*   col_idx = (int*)d_ws;            // NE ints
    float* marg_e  = (float*)d_ws + NE;     // NE floats
    float* base_e  = marg_e + NE;           // L*NE floats
    float* wde_e   = base_e + LL * NE;      // L*NE floats

    setup_kernel<<<MM, 256, 0, stream>>>(H, llrs, w_llr, w_de, marg_de,
                                         col_idx, marg_e, base_e, wde_e, out);
    bp_kernel<<<MB, NT, 0, stream>>>(synd, errors, llrs, marg_llr, res_w, rhos,
                                     col_idx, marg_e, base_e, wde_e, out);
}

// Round 11
// 146.379 us; speedup vs baseline: 6.3977x; 1.4283x over previous
//
#include <hip/hip_runtime.h>
#include <math.h>

// Problem constants (match reference)
#define MB 8      // batch
#define MM 384    // checks
#define NN 1536   // variables
#define LL 20     // layers
#define RW 8      // row weight of H
#define HE 4      // edges per thread (half row)
#define NE (MM*RW)  // 3072 edges
#define NT 768    // bp block size (2 threads per check row)
#define VP 12     // max column degree supported (validated: R10 absmax=0.0)

// ---------------------------------------------------------------------------
// Fused setup: one block (256 thr = 4 waves) per check row (unchanged).
// ---------------------------------------------------------------------------
__global__ __launch_bounds__(256) void setup_kernel(
    const float* __restrict__ H,
    const float* __restrict__ llrs,
    const float* __restrict__ w_llr,
    const float* __restrict__ w_de,
    const float* __restrict__ marg_de,
    int*   __restrict__ col_idx,
    float* __restrict__ marg_e,
    float* __restrict__ base_e,
    float* __restrict__ wde_e,
    float* __restrict__ out) {
    const int m = blockIdx.x;
    const int t = threadIdx.x;
    const int w = t >> 6, lane = t & 63;
    __shared__ int s_qcol[4][RW];
    __shared__ int s_qcnt[4];
    __shared__ int s_col[RW];

    const float* row = H + (size_t)m * NN;
    int count = 0;
    for (int c0 = w * 384; c0 < (w + 1) * 384; c0 += 64) {
        float v = row[c0 + lane];
        unsigned long long mask = __ballot(v != 0.0f);
        if (v != 0.0f) {
            int pos = count + (int)__popcll(mask & ((1ull << lane) - 1ull));
            if (pos < RW) s_qcol[w][pos] = c0 + lane;
        }
        count += (int)__popcll(mask);
    }
    if (lane == 0) s_qcnt[w] = (count < RW) ? count : RW;
    __syncthreads();
    if (t == 0) {
        int off = 0;
        for (int q = 0; q < 4; ++q)
            for (int i = 0; i < s_qcnt[q]; ++i) {
                if (off < RW) s_col[off] = s_qcol[q][i];
                ++off;
            }
    }
    __syncthreads();

    if (t < RW) {
        int c = s_col[t];
        col_idx[m * RW + t] = c;
        marg_e[m * RW + t]  = marg_de[m * NN + c];
    }
    if (m == 0 && t == 0) out[0] = 0.0f;

    for (int idx = t; idx < LL * RW; idx += 256) {
        int l = idx >> 3;
        int k = idx & 7;
        int c = s_col[k];
        base_e[l * NE + m * RW + k] = llrs[c] * w_llr[l * NN + c];
        wde_e [l * NE + m * RW + k] = w_de[(size_t)l * MM * NN + (size_t)m * NN + c];
    }
}

// ---------------------------------------------------------------------------
// Main BP kernel: 8 blocks, 768 threads = 2 per check row (4 edges each).
// ZERO atomics in the layer loop (R10 measured LDS-atomic pipe occupancy at
// ~2.5 cy/lane-op — the dominant cost). Per layer:
//   top:   owner threads GATHER S and beliefs from dense contribution arrays
//          (register-cached CSC slot lists, avg col degree 2), plain-write
//          s_S; deferred loss for layer l-1.      [barrier A]
//   edge:  check-node update reads s_S[col], writes contributions to private
//          slots: s_cS[k*NT+t] = nm*w_de[l+1], s_cB[k*NT+t] = nm*marg.
//          Conflict-free write pattern.           [barrier B]
// Single-buffer s_S/cS/cB: the two barriers separate all read/write phases.
// ---------------------------------------------------------------------------
__global__ __launch_bounds__(NT) void bp_kernel(
    const float* __restrict__ synd,       // (B,M,1)
    const float* __restrict__ errors,     // (B,N)
    const float* __restrict__ llrs,       // (N)
    const float* __restrict__ marg_llr,   // (N)
    const float* __restrict__ res_w,      // (L)
    const float* __restrict__ rhos,       // (L)
    const int*   __restrict__ col_idx,    // (E)
    const float* __restrict__ marg_e_g,   // (E)
    const float* __restrict__ base_e_g,   // (L,E)
    const float* __restrict__ wde_e_g,    // (L,E)
    float* __restrict__ out) {

    __shared__ float s_S[NN];                 // 6 KB   variable sums (this layer)
    __shared__ float s_cS[NE];                // 12 KB  S contribs  (slot k*NT+t)
    __shared__ float s_cB[NE];                // 12 KB  belief contribs
    __shared__ unsigned short s_vslot[NN*VP]; // 36 KB  CSC slot table
    __shared__ int   s_vdeg[NN];              // 6 KB
    __shared__ float s_rw[LL];
    __shared__ float s_rho[LL];
    __shared__ float s_red[12];

    const int b = blockIdx.x;
    const int t = threadIdx.x;
    const int m = t >> 1;        // check row; edges owned: e = t*HE + k

    // ---- per-thread register state ----
    int col[HE];
    {
        const int4 ci = ((const int4*)col_idx)[t];
        col[0] = ci.x; col[1] = ci.y; col[2] = ci.z; col[3] = ci.w;
    }
    float msg[HE] = {0.0f, 0.0f, 0.0f, 0.0f};
    float marg[HE];
    {
        const float4 mg = ((const float4*)marg_e_g)[t];
        marg[0] = mg.x; marg[1] = mg.y; marg[2] = mg.z; marg[3] = mg.w;
    }
    const float sgn = 1.0f - 2.0f * synd[b * MM + m];

    float bias[2], omeg[2];
    #pragma unroll
    for (int i = 0; i < 2; ++i) {
        int n = t + i * NT;
        bias[i] = llrs[n] * marg_llr[n];
        omeg[i] = 1.0f - errors[b * NN + n];
        s_vdeg[n] = 0;
    }
    // zero contribution slots (layer-0 gather then yields S=0 = msg_0 state)
    #pragma unroll
    for (int k = 0; k < HE; ++k) {
        s_cS[k * NT + t] = 0.0f;
        s_cB[k * NT + t] = 0.0f;
    }
    if (t < LL) { s_rw[t] = res_w[t]; s_rho[t] = rhos[t]; }
    __syncthreads();

    // ---- build CSC slot table (once; atomics OK outside the loop) ----
    #pragma unroll
    for (int k = 0; k < HE; ++k) {
        int c = col[k];
        int pos = atomicAdd(&s_vdeg[c], 1);
        if (pos < VP) s_vslot[c * VP + pos] = (unsigned short)(k * NT + t);
    }
    __syncthreads();

    // ---- cache own variables' slot lists in registers ----
    int deg0 = s_vdeg[t];        if (deg0 > VP) deg0 = VP;
    int deg1 = s_vdeg[t + NT];   if (deg1 > VP) deg1 = VP;
    int sl0[VP], sl1[VP];
    #pragma unroll
    for (int j = 0; j < VP; ++j) {
        sl0[j] = (j < deg0) ? (int)s_vslot[t * VP + j] : 0;
        sl1[j] = (j < deg1) ? (int)s_vslot[(t + NT) * VP + j] : 0;
    }

    // ---- prefetch: bc = base_e[layer 0], wS = wde_e[layer 1] ----
    float bc[HE], wS[HE], bn[HE], wn2[HE];
    {
        const float4 bp4 = ((const float4*)(base_e_g))[t];
        bc[0] = bp4.x; bc[1] = bp4.y; bc[2] = bp4.z; bc[3] = bp4.w;
        const float4 wp4 = ((const float4*)(wde_e_g + 1 * NE))[t];
        wS[0] = wp4.x; wS[1] = wp4.y; wS[2] = wp4.z; wS[3] = wp4.w;
    }

    float loss = 0.0f;
    __syncthreads();

    for (int l = 0; l < LL; ++l) {
        // prefetch base_e[l+1] and wde_e[l+2] (consumed next layer)
        {
            int lb = (l + 1 < LL) ? (l + 1) : (LL - 1);
            int lw = (l + 2 < LL) ? (l + 2) : (LL - 1);
            const float4 bp4 = ((const float4*)(base_e_g + lb * NE))[t];
            bn[0]  = bp4.x; bn[1]  = bp4.y; bn[2]  = bp4.z; bn[3]  = bp4.w;
            const float4 wp4 = ((const float4*)(wde_e_g + lw * NE))[t];
            wn2[0] = wp4.x; wn2[1] = wp4.y; wn2[2] = wp4.z; wn2[3] = wp4.w;
        }

        // ---- owner gather: S for this layer + beliefs/loss for layer l-1 ----
        {
            float S0 = 0.0f, S1 = 0.0f;
            float bel0 = bias[0], bel1 = bias[1];
            #pragma unroll
            for (int j = 0; j < VP; ++j) {
                if (j < deg0) { S0 += s_cS[sl0[j]]; bel0 += s_cB[sl0[j]]; }
                if (j < deg1) { S1 += s_cS[sl1[j]]; bel1 += s_cB[sl1[j]]; }
            }
            s_S[t]      = S0;
            s_S[t + NT] = S1;
            if (l > 0) {
                const float rr = s_rho[l - 1];
                float sp0 = fmaxf(bel0, 0.0f) + __logf(1.0f + __expf(-fabsf(bel0)));
                float sp1 = fmaxf(bel1, 0.0f) + __logf(1.0f + __expf(-fabsf(bel1)));
                loss += rr * ((sp0 - omeg[0] * bel0) + (sp1 - omeg[1] * bel1));
            }
        }
        __syncthreads();   // barrier A: s_S ready; old cS/cB fully consumed

        const float rw_ = s_rw[l];

        // ---- check-node update over this thread's 4 edges ----
        float d[HE];
        #pragma unroll
        for (int k = 0; k < HE; ++k) {
            float te = bc[k] + s_S[col[k]] - msg[k];
            float e  = __expf(te);                          // v_exp_f32
            float dd = 1.0f - 2.0f * __builtin_amdgcn_rcpf(e + 1.0f);
            dd = fminf(fmaxf(dd, -1.0f), 1.0f);             // guard rcp rounding
            if (dd == 0.0f) dd = 1.0f;                      // jnp.where(d==0,1,d)
            d[k] = dd;
        }
        float p01 = d[0] * d[1], p23 = d[2] * d[3];
        float p4  = p01 * p23;
        float pot = __shfl_xor(p4, 1, 64);                  // partner half's product
        float ptot = p4 * pot;                              // full row product

        #pragma unroll
        for (int k = 0; k < HE; ++k) {
            float x  = ptot * __builtin_amdgcn_rcpf(d[k]);  // reference's p/d
            float r  = (1.0f + x) * __builtin_amdgcn_rcpf(1.0f - x);
            float nm = sgn * __logf(r) + rw_ * msg[k];      // 2*atanh*sgn + res*msg
            msg[k] = nm;
            s_cS[k * NT + t] = nm * wS[k];                  // S contrib (plain write)
            s_cB[k * NT + t] = nm * marg[k];                // bel contrib (plain write)
        }

        // rotate prefetched weights
        #pragma unroll
        for (int k = 0; k < HE; ++k) { bc[k] = bn[k]; wS[k] = wn2[k]; }

        __syncthreads();   // barrier B: cS/cB complete for next layer's gather
    }

    // tail: loss for the last layer
    {
        const float rr = s_rho[LL - 1];
        float bel0 = bias[0], bel1 = bias[1];
        #pragma unroll
        for (int j = 0; j < VP; ++j) {
            if (j < deg0) bel0 += s_cB[sl0[j]];
            if (j < deg1) bel1 += s_cB[sl1[j]];
        }
        float sp0 = fmaxf(bel0, 0.0f) + __logf(1.0f + __expf(-fabsf(bel0)));
        float sp1 = fmaxf(bel1, 0.0f) + __logf(1.0f + __expf(-fabsf(bel1)));
        loss += rr * ((sp0 - omeg[0] * bel0) + (sp1 - omeg[1] * bel1));
    }

    // ---- block-wide loss reduction (12 waves) ----
    #pragma unroll
    for (int off = 32; off > 0; off >>= 1)
        loss += __shfl_down(loss, off, 64);
    int wave = t >> 6, lane = t & 63;
    if (lane == 0) s_red[wave] = loss;
    __syncthreads();
    if (t == 0) {
        float tot = 0.0f;
        #pragma unroll
        for (int w = 0; w < 12; ++w) tot += s_red[w];
        atomicAdd(out, tot * (1.0f / (float)MB));
    }
}

// ---------------------------------------------------------------------------
extern "C" void kernel_launch(void* const* d_in, const int* in_sizes, int n_in,
                              void* d_out, int out_size, void* d_ws, size_t ws_size,
                              hipStream_t stream) {
    const float* synd     = (const float*)d_in[0];
    const float* errors   = (const float*)d_in[1];
    const float* H        = (const float*)d_in[2];
    const float* llrs     = (const float*)d_in[3];
    const float* w_de     = (const float*)d_in[4];
    const float* w_llr    = (const float*)d_in[5];
    const float* marg_de  = (const float*)d_in[6];
    const float* marg_llr = (const float*)d_in[7];
    const float* res_w    = (const float*)d_in[8];
    const float* rhos     = (const float*)d_in[9];
    float* out = (float*)d_out;

    // Workspace layout (4-byte elements, 16B-aligned partitions)
    int*   col_idx = (int*)d_ws;            // NE ints
    float* marg_e  = (float*)d_ws + NE;     // NE floats
    float* base_e  = marg_e + NE;           // L*NE floats
    float* wde_e   = base_e + LL * NE;      // L*NE floats

    setup_kernel<<<MM, 256, 0, stream>>>(H, llrs, w_llr, w_de, marg_de,
                                         col_idx, marg_e, base_e, wde_e, out);
    bp_kernel<<<MB, NT, 0, stream>>>(synd, errors, llrs, marg_llr, res_w, rhos,
                                     col_idx, marg_e, base_e, wde_e, out);
}